// Round 7
// baseline (196.781 us; speedup 1.0000x reference)
//
#include <hip/hip_runtime.h>
#include <hip/hip_bf16.h>
#include <stdint.h>

// T=1024, D=4096, O=4096, R=16, L=16. fp32 device buffers.
// R10: merged k12 (main+shrink), 191us. k12=45us, MfmaUtil 33%.
// R11/R12 NULL: un-clobbering inputs changed nothing; harness cost fixed.
// R13 FAILED (226us, k12=106): W cvt via reg-staging with load-use ADJACENCY
//   (load->vmcnt0->cvt->ds_write inline) serialized the K-loop.
// R14 (187.8us, k12=44.9): split-K=2 + masked a_sel. k12 is structure-bound
//   (813 TF = m97-class ceiling at this shape); its own HBM bytes are free.
// R15/R16 FAILED (196.6us, k12=71.7 > abort 55): fp32 B staged in LDS.
//   Failure modes: 48KB LDS (3 blk/CU), 12 gload_lds + 48KB drained/step,
//   cvt on the FRAGMENT path (2x ds_read_b128 per frag, redundant cvt).
// R17: last W-fusion variant — T14 issue-early/write-late reg-staging:
//   critical path byte-identical to R14 (32KB LDS, bf16 sB, same swizzle,
//   same fragment reads, same barriers). B fp32 loads for step k+1 issue
//   right after step k's barrier1 and fly across the MFMA phase; top of
//   step k+1 does cvt+ds_write only (data landed; cvt once, staging path).
//   m249 measured this config at -16% GEMM worst case -> k12 <= 54us; convert
//   drops W (132->36 MB, ~6.5us). Net win -6..-13us at both bounds.
//   ABORT: k12 > 58us => W-fusion exhausted; revert to R14, declare ceiling.
#define T_TOK 1024
#define D_IN  4096
#define O_OUT 4096
#define RANK  16

#define BM 128
#define BN 128
#define BKM 64                 // main-GEMM K-tile
#define KCH 2048               // main-GEMM K per split-K chunk (split-K=2)
#define PART_ELEMS 4194304     // 1024*4096 per K-chunk partial (bf16)
#define ASEL_STRIDE 16384      // 1024*16 per shrink K-chunk (fp32)

typedef __bf16 bf16;
typedef __bf16 bf16x4 __attribute__((ext_vector_type(4)));
typedef __bf16 bf16x8 __attribute__((ext_vector_type(8)));
typedef float  v4f    __attribute__((ext_vector_type(4)));

// ws layout (bytes) — 28.5 MB, within proven budget
#define WS_XB    0          // x  bf16 [1024,4096]           8 MB
#define WS_AB    8388608    // A_all bf16 [256,4096]         2 MB
#define WS_LBB   10485760   // lora_b bf16 [16,4096,16]      2 MB
#define WS_PART  12582912   // partial bf16 [2][1024][4096] 16 MB

#define ASYNC_COPY16(gptr, lptr)                                                   \
  __builtin_amdgcn_global_load_lds((const __attribute__((address_space(1))) void*)(gptr), \
                                   (__attribute__((address_space(3))) void*)(lptr), 16, 0, 0)

__device__ inline bf16x8 cvt_pack8(v4f a, v4f b) {
    bf16x8 r;
    r[0] = (bf16)a[0]; r[1] = (bf16)a[1]; r[2] = (bf16)a[2]; r[3] = (bf16)a[3];
    r[4] = (bf16)b[0]; r[5] = (bf16)b[1]; r[6] = (bf16)b[2]; r[7] = (bf16)b[3];
    return r;
}

// ---------------------------------------------------------------------------
// K0: fp32 -> bf16 convert of x, A_all, lora_b only (W is consumed fp32 by
// k12 now). 786432 chunks of 8 elems = 3072 blocks.
// ---------------------------------------------------------------------------
__global__ __launch_bounds__(256) void convert_kernel(
    const float* __restrict__ x, const float* __restrict__ la,
    const float* __restrict__ lb,
    bf16* __restrict__ xb, bf16* __restrict__ ab, bf16* __restrict__ lbb)
{
    const int c = blockIdx.x * 256 + threadIdx.x;
    const float* src; bf16* dst; int off;
    if (c < 524288)       { src = x;  dst = xb;  off = c; }
    else if (c < 655360)  { src = la; dst = ab;  off = c - 524288; }
    else                  { src = lb; dst = lbb; off = c - 655360; }
    const size_t e = (size_t)off * 8;
    v4f lo = *(const v4f*)&src[e];
    v4f hi = *(const v4f*)&src[e + 4];
    *(bf16x8*)&dst[e] = cvt_pack8(lo, hi);
}

// ---------------------------------------------------------------------------
// K12: merged launch, 1536 blocks.
//  blocks [0,512):     main-GEMM partial, split-K=2.
//    A: global_load_lds from xb (bf16) — unchanged from R14.
//    B: T14 reg-staged from W fp32: loads for step k+1 issued after step k's
//       barrier1 (fly over MFMA phase); cvt+ds_write at top of step k+1 into
//       the SAME bf16 swizzled slots as R14. LDS stays 32 KB.
//  blocks [512,1536):  shrink partial, masked write (only idx[t]'s lora).
// ---------------------------------------------------------------------------
__global__ __launch_bounds__(256, 3) void k12_kernel(
    const bf16* __restrict__ xb, const float* __restrict__ wgt,
    const bf16* __restrict__ ab, const int* __restrict__ idx,
    bf16* __restrict__ part, float* __restrict__ a_sel)
{
    __shared__ __align__(16) bf16 sA[BM * BKM];   // 16 KB
    __shared__ __align__(16) bf16 sB[BN * BKM];   // 16 KB

    const int tid = threadIdx.x, wid = tid >> 6, lane = tid & 63;
    const int bid = blockIdx.x;

    if (bid < 512) {
        // ---------------- main GEMM partial (split-K=2) ----------------
        const int bn = bid & 31, bm = (bid >> 5) & 7, kc = bid >> 8;  // kc in {0,1}

        const bf16*  __restrict__ gA = xb  + (size_t)bm * BM * D_IN + kc * KCH;
        const float* __restrict__ gW = wgt + (size_t)bn * BN * D_IN + kc * KCH;

        const int wm = (wid & 1) * 64, wn = (wid >> 1) * 64;
        const int lrow = lane & 15, quad = lane >> 4;

        v4f acc[4][4];
        const v4f vz = {0.f, 0.f, 0.f, 0.f};
#pragma unroll
        for (int mi = 0; mi < 4; ++mi)
#pragma unroll
            for (int ni = 0; ni < 4; ++ni) acc[mi][ni] = vz;

        // Per-thread B slots: s = wid*64 + lane + it*256, it=0..3.
        // Slot s: row=s>>3, pos=s&7 holds global 8-elem chunk pos^(row&7).
        // Each 16B bf16 slot = 8 fp32 = 2 v4f of W.
        v4f wr[8];
        // Prologue: load B data for step 0 into regs.
#pragma unroll
        for (int it = 0; it < 4; ++it) {
            const int s   = wid * 64 + lane + it * 256;
            const int row = s >> 3, pos = s & 7;
            const int kc8 = pos ^ (row & 7);
            const size_t gw = (size_t)row * D_IN + kc8 * 8;
            wr[2 * it]     = *(const v4f*)&gW[gw];
            wr[2 * it + 1] = *(const v4f*)&gW[gw + 4];
        }

        for (int k0 = 0; k0 < KCH; k0 += BKM) {
            // Staging: A async gload_lds (step k0) + B cvt+ds_write from wr
            // (wr holds step-k0 data, loaded one step earlier).
#pragma unroll
            for (int it = 0; it < 4; ++it) {
                const int s   = wid * 64 + lane + it * 256;
                const int row = s >> 3, pos = s & 7;
                const int kc8 = pos ^ (row & 7);
                const size_t goff = (size_t)row * D_IN + k0 + kc8 * 8;
                char* la_ = (char*)sA + (size_t)(wid * 64 + it * 256) * 16;
                ASYNC_COPY16(gA + goff, la_);
                *(bf16x8*)((char*)sB + (size_t)s * 16) =
                    cvt_pack8(wr[2 * it], wr[2 * it + 1]);
            }
            __syncthreads();   // drains A vmcnt + B lgkm

            // T14 issue-early: B fp32 loads for step k0+64 fly over the MFMA
            // phase (~1.2us/step >> HBM latency); consumed at next step's top.
            if (k0 + BKM < KCH) {
#pragma unroll
                for (int it = 0; it < 4; ++it) {
                    const int s   = wid * 64 + lane + it * 256;
                    const int row = s >> 3, pos = s & 7;
                    const int kc8 = pos ^ (row & 7);
                    const size_t gw = (size_t)row * D_IN + (k0 + BKM) + kc8 * 8;
                    wr[2 * it]     = *(const v4f*)&gW[gw];
                    wr[2 * it + 1] = *(const v4f*)&gW[gw + 4];
                }
            }

#pragma unroll
            for (int ks = 0; ks < 2; ++ks) {
                bf16x8 af[4], bfv[4];
#pragma unroll
                for (int mi = 0; mi < 4; ++mi) {
                    const int row = wm + mi * 16 + lrow;
                    const int pos = (ks * 4 + quad) ^ (row & 7);
                    af[mi] = *(const bf16x8*)&sA[row * BKM + pos * 8];
                }
#pragma unroll
                for (int ni = 0; ni < 4; ++ni) {
                    const int row = wn + ni * 16 + lrow;
                    const int pos = (ks * 4 + quad) ^ (row & 7);
                    bfv[ni] = *(const bf16x8*)&sB[row * BKM + pos * 8];
                }
#pragma unroll
                for (int mi = 0; mi < 4; ++mi)
#pragma unroll
                    for (int ni = 0; ni < 4; ++ni)
                        acc[mi][ni] = __builtin_amdgcn_mfma_f32_16x16x32_bf16(
                            af[mi], bfv[ni], acc[mi][ni], 0, 0, 0);
            }
            __syncthreads();
        }

        bf16* __restrict__ op = part + (size_t)kc * PART_ELEMS;
        // C/D layout (16x16x32): col=lane&15, row=quad*4+reg
#pragma unroll
        for (int mi = 0; mi < 4; ++mi)
#pragma unroll
            for (int r = 0; r < 4; ++r) {
                const int t = bm * BM + wm + mi * 16 + quad * 4 + r;
#pragma unroll
                for (int ni = 0; ni < 4; ++ni) {
                    const int o = bn * BN + wn + ni * 16 + lrow;
                    op[(size_t)t * O_OUT + o] = (bf16)acc[mi][ni][r];
                }
            }
    } else {
        // ---------------- shrink GEMM partial (masked write) ----------------
        const int b2 = bid - 512;
        const int bm = b2 & 15, bn = (b2 >> 4) & 3, kc = b2 >> 6;

        bf16* sX  = sA;                // first 4 KB of each buffer used
        bf16* sAl = sB;

        const bf16* __restrict__ gX = xb + (size_t)bm * 64 * D_IN + kc * 256;
        const bf16* __restrict__ gA = ab + (size_t)bn * 64 * D_IN + kc * 256;

        const int wm = (wid & 1) * 32, wn = (wid >> 1) * 32;
        const int lrow = lane & 15, kq = (lane >> 4) * 8;
        const int row = tid >> 2, ch = tid & 3;

        v4f acc[2][2];
        const v4f vz = {0.f, 0.f, 0.f, 0.f};
        acc[0][0] = vz; acc[0][1] = vz; acc[1][0] = vz; acc[1][1] = vz;

        for (int k0 = 0; k0 < 256; k0 += 32) {
            const size_t goff = (size_t)row * D_IN + k0 + ch * 8;
            ASYNC_COPY16(gX + goff, (char*)sX + wid * 1024);
            ASYNC_COPY16(gA + goff, (char*)sAl + wid * 1024);
            __syncthreads();
            bf16x8 xf[2], af[2];
#pragma unroll
            for (int mi = 0; mi < 2; ++mi)
                xf[mi] = *(const bf16x8*)&sX[(wm + mi * 16 + lrow) * 32 + kq];
#pragma unroll
            for (int ni = 0; ni < 2; ++ni)
                af[ni] = *(const bf16x8*)&sAl[(wn + ni * 16 + lrow) * 32 + kq];
#pragma unroll
            for (int mi = 0; mi < 2; ++mi)
#pragma unroll
                for (int ni = 0; ni < 2; ++ni)
                    acc[mi][ni] = __builtin_amdgcn_mfma_f32_16x16x32_bf16(
                        xf[mi], af[ni], acc[mi][ni], 0, 0, 0);
            __syncthreads();
        }

        // Masked C-write: n-tile (bn*64+wn+ni*16) is 16-aligned; matches a
        // token's lora iff n-tile == idx[t]*16. 1 MB total vs 16 MB.
        float* __restrict__ op = a_sel + (size_t)kc * ASEL_STRIDE;
        const int colbase = bn * 64 + wn;
#pragma unroll
        for (int mi = 0; mi < 2; ++mi)
#pragma unroll
            for (int r = 0; r < 4; ++r) {
                const int t = bm * 64 + wm + mi * 16 + (lane >> 4) * 4 + r;
                const int l = idx[t];
                if (l >= 0) {
#pragma unroll
                    for (int ni = 0; ni < 2; ++ni) {
                        if (colbase + ni * 16 == l * 16)
                            op[(size_t)t * RANK + (lane & 15)] = acc[mi][ni][r];
                    }
                }
            }
    }
}

// ---------------------------------------------------------------------------
// K3: out[t,o] = part[0][t][o] + part[1][t][o] + bias[o] + LoRA expand.
// Grid (1024): one block per token; 16 o/thread (4 x v4f).
// ---------------------------------------------------------------------------
__global__ __launch_bounds__(256) void epilogue_kernel(
    const bf16* __restrict__ part, const float* __restrict__ bias,
    const bf16* __restrict__ lbb, const int* __restrict__ idx,
    const float* __restrict__ a_sel, float* __restrict__ out)
{
    const int t   = blockIdx.x;
    const int tid = threadIdx.x;
    const int l   = idx[t];

    // Parallel a_sel reduction: thread i in [0,256) = (kc=i>>4, r=i&15)
    __shared__ float sred[256];
    __shared__ float sa[RANK];
    {
        float v = 0.0f;
        if (l >= 0) {
            const int kc = tid >> 4, r = tid & 15;
            v = a_sel[(size_t)kc * ASEL_STRIDE + (size_t)t * RANK + r];
        }
        sred[tid] = v;
    }
    __syncthreads();
    if (tid < RANK) {
        float v = 0.0f;
#pragma unroll
        for (int kc = 0; kc < 16; ++kc) v += sred[kc * 16 + tid];
        sa[tid] = v;
    }
    __syncthreads();

#pragma unroll
    for (int c = 0; c < 4; ++c) {
        const int o = c * 1024 + tid * 4;
        const size_t po = (size_t)t * O_OUT + o;
        v4f s = *(const v4f*)&bias[o];
#pragma unroll
        for (int p = 0; p < 2; ++p) {
            bf16x4 pv = *(const bf16x4*)&part[(size_t)p * PART_ELEMS + po];
#pragma unroll
            for (int j = 0; j < 4; ++j) s[j] += (float)pv[j];
        }
        if (l >= 0) {
#pragma unroll
            for (int j = 0; j < 4; ++j) {
                const bf16* bp = lbb + ((size_t)l * O_OUT + o + j) * RANK;
                bf16x8 b0 = *(const bf16x8*)bp;
                bf16x8 b1 = *(const bf16x8*)(bp + 8);
                float y = 0.0f;
#pragma unroll
                for (int r = 0; r < 8; ++r) y += sa[r] * (float)b0[r];
#pragma unroll
                for (int r = 0; r < 8; ++r) y += sa[8 + r] * (float)b1[r];
                s[j] += y;
            }
        }
        *(v4f*)&out[po] = s;
    }
}

extern "C" void kernel_launch(void* const* d_in, const int* in_sizes, int n_in,
                              void* d_out, int out_size, void* d_ws, size_t ws_size,
                              hipStream_t stream) {
    const float* x    = (const float*)d_in[0];   // [1024, 4096]
    const float* wgt  = (const float*)d_in[1];   // [4096, 4096]
    const float* bias = (const float*)d_in[2];   // [4096]
    const float* la   = (const float*)d_in[3];   // [16,1,16,4096] = [256,4096]
    const float* lb   = (const float*)d_in[4];   // [16,1,4096,16]
    const int*   idx  = (const int*)d_in[5];     // [1024]
    float* out = (float*)d_out;

    char* ws = (char*)d_ws;
    bf16* xb      = (bf16*)(ws + WS_XB);
    bf16* ab      = (bf16*)(ws + WS_AB);
    bf16* lbb     = (bf16*)(ws + WS_LBB);
    bf16* partial = (bf16*)(ws + WS_PART);   // W stays live -> partial in ws

    // a_sel (1 MB) -> dead fp32 x (proven-safe clobber; convert consumes x
    // before k12 writes it; stream-ordered).
    float* a_sel = (float*)d_in[0];

    convert_kernel<<<dim3(3072), dim3(256), 0, stream>>>(
        x, la, lb, xb, ab, lbb);
    k12_kernel<<<dim3(1536), dim3(256), 0, stream>>>(
        xb, wgt, ab, idx, partial, a_sel);
    epilogue_kernel<<<dim3(T_TOK), dim3(256), 0, stream>>>(
        partial, bias, lbb, idx, a_sel, out);
}

// Round 8
// 190.455 us; speedup vs baseline: 1.0332x; 1.0332x over previous
//
#include <hip/hip_runtime.h>
#include <hip/hip_bf16.h>
#include <stdint.h>

// T=1024, D=4096, O=4096, R=16, L=16. fp32 device buffers.
// R9:  device-scope fence per block -> 6x serialization; separate epilogue wins.
// R10: merged k12 (main+shrink), 191us. k12=45us, MfmaUtil 33%.
// R11/R12 NULL: un-clobbering inputs changed nothing; harness cost (~112us) fixed.
// R13 FAILED (226us, k12=106): W cvt reg-staged inline -> serialized K-loop.
// R14 (187.8us, k12=44.9): split-K=2 + masked a_sel. BEST. k12 structure-bound
//   (813 TF, m97-class ceiling); k12's own HBM bytes are free (R14 PMC).
// R15/R16 FAILED (196.6us, k12=71.7): fp32 B in LDS (48KB, cvt on frag path).
// R17 FAILED (196.8us, k12=75.6): T14 issue-early reg-staging — compiler sank
//   W loads to use point (VGPR=80, wr not kept live) -> R13 disease again.
//   W-FUSION EXHAUSTED (3 variants). W cvt stays in streaming convert.
// R18: revert to R14 verbatim + ONE isolated off-critical-path experiment:
//   convert kernel grid-strided at 2048 blocks (G11) vs 11264 one-shot.
//   Predict: k12 back to 44.9/32%/59.7MB/17.3MB; dur 184-189.
#define T_TOK 1024
#define D_IN  4096
#define O_OUT 4096
#define RANK  16

#define BM 128
#define BN 128
#define BKM 64                 // main-GEMM K-tile
#define KCH 2048               // main-GEMM K per split-K chunk (split-K=2)
#define PART_ELEMS 4194304     // 1024*4096 per K-chunk partial (bf16)
#define ASEL_STRIDE 16384      // 1024*16 per shrink K-chunk (fp32)

#define CVT_CHUNKS 2883584     // 2097152 (W) + 524288 (x) + 131072 (la) + 131072 (lb)

typedef __bf16 bf16;
typedef __bf16 bf16x4 __attribute__((ext_vector_type(4)));
typedef __bf16 bf16x8 __attribute__((ext_vector_type(8)));
typedef float  v4f    __attribute__((ext_vector_type(4)));

// ws layout (bytes) — 44.1 MB, within proven budget
#define WS_WB    0          // W  bf16 [4096,4096]        32 MB
#define WS_XB    33554432   // x  bf16 [1024,4096]         8 MB
#define WS_AB    41943040   // A_all bf16 [256,4096]       2 MB
#define WS_LBB   44040192   // lora_b bf16 [16,4096,16]    2 MB

#define ASYNC_COPY16(gptr, lptr)                                                   \
  __builtin_amdgcn_global_load_lds((const __attribute__((address_space(1))) void*)(gptr), \
                                   (__attribute__((address_space(3))) void*)(lptr), 16, 0, 0)

__device__ inline bf16x8 cvt_pack8(v4f a, v4f b) {
    bf16x8 r;
    r[0] = (bf16)a[0]; r[1] = (bf16)a[1]; r[2] = (bf16)a[2]; r[3] = (bf16)a[3];
    r[4] = (bf16)b[0]; r[5] = (bf16)b[1]; r[6] = (bf16)b[2]; r[7] = (bf16)b[3];
    return r;
}

// ---------------------------------------------------------------------------
// K0: fp32 -> bf16 convert of W, x, A_all, lora_b. 8-elem chunks, grid-stride
// at 2048 blocks (G11: cap ~2048, stride the rest).
// ---------------------------------------------------------------------------
__global__ __launch_bounds__(256) void convert_kernel(
    const float* __restrict__ w, const float* __restrict__ x,
    const float* __restrict__ la, const float* __restrict__ lb,
    bf16* __restrict__ wb, bf16* __restrict__ xb,
    bf16* __restrict__ ab, bf16* __restrict__ lbb)
{
    const int stride = 2048 * 256;
    for (int c = blockIdx.x * 256 + threadIdx.x; c < CVT_CHUNKS; c += stride) {
        const float* src; bf16* dst; int off;
        if (c < 2097152)      { src = w;  dst = wb;  off = c; }
        else if (c < 2621440) { src = x;  dst = xb;  off = c - 2097152; }
        else if (c < 2752512) { src = la; dst = ab;  off = c - 2621440; }
        else                  { src = lb; dst = lbb; off = c - 2752512; }
        const size_t e = (size_t)off * 8;
        v4f lo = *(const v4f*)&src[e];
        v4f hi = *(const v4f*)&src[e + 4];
        *(bf16x8*)&dst[e] = cvt_pack8(lo, hi);
    }
}

// ---------------------------------------------------------------------------
// K12: merged launch, 1536 blocks.
//  blocks [0,512):     main-GEMM partial  part[kc][t][o] = x@W^T (K-chunk,
//                      split-K=2). BK=64, XOR-swizzled LDS (0 conflicts).
//  blocks [512,1536):  shrink partial, masked write: only idx[t]'s lora
//                      columns land in a_sel[kc][t][0..15].
// ---------------------------------------------------------------------------
__global__ __launch_bounds__(256, 4) void k12_kernel(
    const bf16* __restrict__ xb, const bf16* __restrict__ wb,
    const bf16* __restrict__ ab, const int* __restrict__ idx,
    bf16* __restrict__ part, float* __restrict__ a_sel)
{
    __shared__ __align__(16) bf16 sA[BM * BKM];   // 16 KB
    __shared__ __align__(16) bf16 sB[BN * BKM];   // 16 KB

    const int tid = threadIdx.x, wid = tid >> 6, lane = tid & 63;
    const int bid = blockIdx.x;

    if (bid < 512) {
        // ---------------- main GEMM partial (split-K=2) ----------------
        const int bn = bid & 31, bm = (bid >> 5) & 7, kc = bid >> 8;  // kc in {0,1}

        const bf16* __restrict__ gA = xb + (size_t)bm * BM * D_IN + kc * KCH;
        const bf16* __restrict__ gB = wb + (size_t)bn * BN * D_IN + kc * KCH;

        const int wm = (wid & 1) * 64, wn = (wid >> 1) * 64;
        const int lrow = lane & 15, quad = lane >> 4;

        v4f acc[4][4];
        const v4f vz = {0.f, 0.f, 0.f, 0.f};
#pragma unroll
        for (int mi = 0; mi < 4; ++mi)
#pragma unroll
            for (int ni = 0; ni < 4; ++ni) acc[mi][ni] = vz;

        for (int k0 = 0; k0 < KCH; k0 += BKM) {
            // slot s: row=s>>3, pos=s&7 holds global k-chunk pos^(row&7)
#pragma unroll
            for (int it = 0; it < 4; ++it) {
                const int s   = wid * 64 + lane + it * 256;
                const int row = s >> 3, pos = s & 7;
                const int kc8 = pos ^ (row & 7);
                const size_t goff = (size_t)row * D_IN + k0 + kc8 * 8;
                char* la_ = (char*)sA + (size_t)(wid * 64 + it * 256) * 16;
                char* lb_ = (char*)sB + (size_t)(wid * 64 + it * 256) * 16;
                ASYNC_COPY16(gA + goff, la_);
                ASYNC_COPY16(gB + goff, lb_);
            }
            __syncthreads();

#pragma unroll
            for (int ks = 0; ks < 2; ++ks) {
                bf16x8 af[4], bfv[4];
#pragma unroll
                for (int mi = 0; mi < 4; ++mi) {
                    const int row = wm + mi * 16 + lrow;
                    const int pos = (ks * 4 + quad) ^ (row & 7);
                    af[mi] = *(const bf16x8*)&sA[row * BKM + pos * 8];
                }
#pragma unroll
                for (int ni = 0; ni < 4; ++ni) {
                    const int row = wn + ni * 16 + lrow;
                    const int pos = (ks * 4 + quad) ^ (row & 7);
                    bfv[ni] = *(const bf16x8*)&sB[row * BKM + pos * 8];
                }
#pragma unroll
                for (int mi = 0; mi < 4; ++mi)
#pragma unroll
                    for (int ni = 0; ni < 4; ++ni)
                        acc[mi][ni] = __builtin_amdgcn_mfma_f32_16x16x32_bf16(
                            af[mi], bfv[ni], acc[mi][ni], 0, 0, 0);
            }
            __syncthreads();
        }

        bf16* __restrict__ op = part + (size_t)kc * PART_ELEMS;
        // C/D layout (16x16x32): col=lane&15, row=quad*4+reg
#pragma unroll
        for (int mi = 0; mi < 4; ++mi)
#pragma unroll
            for (int r = 0; r < 4; ++r) {
                const int t = bm * BM + wm + mi * 16 + quad * 4 + r;
#pragma unroll
                for (int ni = 0; ni < 4; ++ni) {
                    const int o = bn * BN + wn + ni * 16 + lrow;
                    op[(size_t)t * O_OUT + o] = (bf16)acc[mi][ni][r];
                }
            }
    } else {
        // ---------------- shrink GEMM partial (masked write) ----------------
        const int b2 = bid - 512;
        const int bm = b2 & 15, bn = (b2 >> 4) & 3, kc = b2 >> 6;

        bf16* sX = sA;                 // reuse first 4 KB of each buffer
        bf16* sAl = sB;

        const bf16* __restrict__ gX = xb + (size_t)bm * 64 * D_IN + kc * 256;
        const bf16* __restrict__ gA = ab + (size_t)bn * 64 * D_IN + kc * 256;

        const int wm = (wid & 1) * 32, wn = (wid >> 1) * 32;
        const int lrow = lane & 15, kq = (lane >> 4) * 8;
        const int row = tid >> 2, ch = tid & 3;

        v4f acc[2][2];
        const v4f vz = {0.f, 0.f, 0.f, 0.f};
        acc[0][0] = vz; acc[0][1] = vz; acc[1][0] = vz; acc[1][1] = vz;

        for (int k0 = 0; k0 < 256; k0 += 32) {
            const size_t goff = (size_t)row * D_IN + k0 + ch * 8;
            ASYNC_COPY16(gX + goff, (char*)sX + wid * 1024);
            ASYNC_COPY16(gA + goff, (char*)sAl + wid * 1024);
            __syncthreads();
            bf16x8 xf[2], af[2];
#pragma unroll
            for (int mi = 0; mi < 2; ++mi)
                xf[mi] = *(const bf16x8*)&sX[(wm + mi * 16 + lrow) * 32 + kq];
#pragma unroll
            for (int ni = 0; ni < 2; ++ni)
                af[ni] = *(const bf16x8*)&sAl[(wn + ni * 16 + lrow) * 32 + kq];
#pragma unroll
            for (int mi = 0; mi < 2; ++mi)
#pragma unroll
                for (int ni = 0; ni < 2; ++ni)
                    acc[mi][ni] = __builtin_amdgcn_mfma_f32_16x16x32_bf16(
                        xf[mi], af[ni], acc[mi][ni], 0, 0, 0);
            __syncthreads();
        }

        // Masked C-write: n-tile (bn*64+wn+ni*16) is 16-aligned; matches a
        // token's lora iff n-tile == idx[t]*16. 1 MB total vs 16 MB.
        float* __restrict__ op = a_sel + (size_t)kc * ASEL_STRIDE;
        const int colbase = bn * 64 + wn;
#pragma unroll
        for (int mi = 0; mi < 2; ++mi)
#pragma unroll
            for (int r = 0; r < 4; ++r) {
                const int t = bm * 64 + wm + mi * 16 + (lane >> 4) * 4 + r;
                const int l = idx[t];
                if (l >= 0) {
#pragma unroll
                    for (int ni = 0; ni < 2; ++ni) {
                        if (colbase + ni * 16 == l * 16)
                            op[(size_t)t * RANK + (lane & 15)] = acc[mi][ni][r];
                    }
                }
            }
    }
}

// ---------------------------------------------------------------------------
// K3: out[t,o] = part[0][t][o] + part[1][t][o] + bias[o] + LoRA expand.
// Grid (1024): one block per token; 16 o/thread (4 x v4f).
// ---------------------------------------------------------------------------
__global__ __launch_bounds__(256) void epilogue_kernel(
    const bf16* __restrict__ part, const float* __restrict__ bias,
    const bf16* __restrict__ lbb, const int* __restrict__ idx,
    const float* __restrict__ a_sel, float* __restrict__ out)
{
    const int t   = blockIdx.x;
    const int tid = threadIdx.x;
    const int l   = idx[t];

    // Parallel a_sel reduction: thread i in [0,256) = (kc=i>>4, r=i&15)
    __shared__ float sred[256];
    __shared__ float sa[RANK];
    {
        float v = 0.0f;
        if (l >= 0) {
            const int kc = tid >> 4, r = tid & 15;
            v = a_sel[(size_t)kc * ASEL_STRIDE + (size_t)t * RANK + r];
        }
        sred[tid] = v;
    }
    __syncthreads();
    if (tid < RANK) {
        float v = 0.0f;
#pragma unroll
        for (int kc = 0; kc < 16; ++kc) v += sred[kc * 16 + tid];
        sa[tid] = v;
    }
    __syncthreads();

#pragma unroll
    for (int c = 0; c < 4; ++c) {
        const int o = c * 1024 + tid * 4;
        const size_t po = (size_t)t * O_OUT + o;
        v4f s = *(const v4f*)&bias[o];
#pragma unroll
        for (int p = 0; p < 2; ++p) {
            bf16x4 pv = *(const bf16x4*)&part[(size_t)p * PART_ELEMS + po];
#pragma unroll
            for (int j = 0; j < 4; ++j) s[j] += (float)pv[j];
        }
        if (l >= 0) {
#pragma unroll
            for (int j = 0; j < 4; ++j) {
                const bf16* bp = lbb + ((size_t)l * O_OUT + o + j) * RANK;
                bf16x8 b0 = *(const bf16x8*)bp;
                bf16x8 b1 = *(const bf16x8*)(bp + 8);
                float y = 0.0f;
#pragma unroll
                for (int r = 0; r < 8; ++r) y += sa[r] * (float)b0[r];
#pragma unroll
                for (int r = 0; r < 8; ++r) y += sa[8 + r] * (float)b1[r];
                s[j] += y;
            }
        }
        *(v4f*)&out[po] = s;
    }
}

extern "C" void kernel_launch(void* const* d_in, const int* in_sizes, int n_in,
                              void* d_out, int out_size, void* d_ws, size_t ws_size,
                              hipStream_t stream) {
    const float* x    = (const float*)d_in[0];   // [1024, 4096]
    const float* wgt  = (const float*)d_in[1];   // [4096, 4096]
    const float* bias = (const float*)d_in[2];   // [4096]
    const float* la   = (const float*)d_in[3];   // [16,1,16,4096] = [256,4096]
    const float* lb   = (const float*)d_in[4];   // [16,1,4096,16]
    const int*   idx  = (const int*)d_in[5];     // [1024]
    float* out = (float*)d_out;

    char* ws = (char*)d_ws;
    bf16* wb  = (bf16*)(ws + WS_WB);
    bf16* xb  = (bf16*)(ws + WS_XB);
    bf16* ab  = (bf16*)(ws + WS_AB);
    bf16* lbb = (bf16*)(ws + WS_LBB);

    // Dead-input scratch (proven safe R10-R14; convert consumes both inputs
    // before k12 overwrites; stream-ordered; clobber cost measured ~0):
    //   fp32 W (64 MB) -> bf16 partial [2][1024][4096] (16 MB)
    //   fp32 x (16 MB) -> fp32 a_sel  [16][1024][16]   (1 MB)
    bf16*  partial = (bf16*)d_in[1];
    float* a_sel   = (float*)d_in[0];

    convert_kernel<<<dim3(2048), dim3(256), 0, stream>>>(
        wgt, x, la, lb, wb, xb, ab, lbb);
    k12_kernel<<<dim3(1536), dim3(256), 0, stream>>>(
        xb, wb, ab, idx, partial, a_sel);
    epilogue_kernel<<<dim3(T_TOK), dim3(256), 0, stream>>>(
        partial, bias, lbb, idx, a_sel, out);
}

// Round 9
// 188.791 us; speedup vs baseline: 1.0423x; 1.0088x over previous
//
#include <hip/hip_runtime.h>
#include <hip/hip_bf16.h>
#include <stdint.h>

// T=1024, D=4096, O=4096, R=16, L=16. fp32 device buffers.
// R9:  device-scope fence per block -> 6x serialization; separate epilogue wins.
// R10: merged k12 (main+shrink), 191us. k12=45us, MfmaUtil 33%.
// R11/R12 NULL: un-clobbering inputs changed nothing; harness cost (~112us) fixed.
// R13 FAILED (226us, k12=106): W cvt reg-staged inline -> serialized K-loop.
// R14 (187.8us, k12=44.9): split-K=2 + masked a_sel. BEST.
// R15/R16 FAILED (196.6us, k12=71.7): fp32 B in LDS (48KB, cvt on frag path).
// R17 FAILED (196.8us, k12=75.6): T14 issue-early reg-staging — compiler sank
//   W loads to use point. W-FUSION EXHAUSTED (3 variants).
// R18 (190.5us): R14 GEMM restored (k12=45.3, counters match) + grid-stride
//   2048-block convert -> read as small loss vs R14's one-shot. Reverted.
// R19 = R14 EXACT (lock in best): one-shot 11264-block convert, split-K=2
//   main GEMM, masked a_sel shrink, lean epilogue.
//   Closed directions: k12 = 813 TF m97-structure ceiling (8-phase
//   inapplicable at M=1024: 256^2 tiling -> 64-128 blocks, underutilized;
//   128^2+8ph = m232 null quadrant); W-fusion 3x failed; k12 bytes free;
//   convert/epilogue at BW floor; ~112us harness fixed (R11/R12).
#define T_TOK 1024
#define D_IN  4096
#define O_OUT 4096
#define RANK  16

#define BM 128
#define BN 128
#define BKM 64                 // main-GEMM K-tile
#define KCH 2048               // main-GEMM K per split-K chunk (split-K=2)
#define PART_ELEMS 4194304     // 1024*4096 per K-chunk partial (bf16)
#define ASEL_STRIDE 16384      // 1024*16 per shrink K-chunk (fp32)

typedef __bf16 bf16;
typedef __bf16 bf16x4 __attribute__((ext_vector_type(4)));
typedef __bf16 bf16x8 __attribute__((ext_vector_type(8)));
typedef float  v4f    __attribute__((ext_vector_type(4)));

// ws layout (bytes) — 44.1 MB, within proven budget
#define WS_WB    0          // W  bf16 [4096,4096]        32 MB
#define WS_XB    33554432   // x  bf16 [1024,4096]         8 MB
#define WS_AB    41943040   // A_all bf16 [256,4096]       2 MB
#define WS_LBB   44040192   // lora_b bf16 [16,4096,16]    2 MB

#define ASYNC_COPY16(gptr, lptr)                                                   \
  __builtin_amdgcn_global_load_lds((const __attribute__((address_space(1))) void*)(gptr), \
                                   (__attribute__((address_space(3))) void*)(lptr), 16, 0, 0)

__device__ inline bf16x8 cvt_pack8(v4f a, v4f b) {
    bf16x8 r;
    r[0] = (bf16)a[0]; r[1] = (bf16)a[1]; r[2] = (bf16)a[2]; r[3] = (bf16)a[3];
    r[4] = (bf16)b[0]; r[5] = (bf16)b[1]; r[6] = (bf16)b[2]; r[7] = (bf16)b[3];
    return r;
}

// ---------------------------------------------------------------------------
// K0: fp32 -> bf16 convert of W, x, A_all, lora_b. One 8-elem chunk/thread,
// one-shot 11264 blocks (measured faster than 2048-block grid-stride, R18).
// ---------------------------------------------------------------------------
__global__ __launch_bounds__(256) void convert_kernel(
    const float* __restrict__ w, const float* __restrict__ x,
    const float* __restrict__ la, const float* __restrict__ lb,
    bf16* __restrict__ wb, bf16* __restrict__ xb,
    bf16* __restrict__ ab, bf16* __restrict__ lbb)
{
    const int c = blockIdx.x * 256 + threadIdx.x;
    const float* src; bf16* dst; int off;
    if (c < 2097152)      { src = w;  dst = wb;  off = c; }
    else if (c < 2621440) { src = x;  dst = xb;  off = c - 2097152; }
    else if (c < 2752512) { src = la; dst = ab;  off = c - 2621440; }
    else                  { src = lb; dst = lbb; off = c - 2752512; }
    const size_t e = (size_t)off * 8;
    v4f lo = *(const v4f*)&src[e];
    v4f hi = *(const v4f*)&src[e + 4];
    *(bf16x8*)&dst[e] = cvt_pack8(lo, hi);
}

// ---------------------------------------------------------------------------
// K12: merged launch, 1536 blocks.
//  blocks [0,512):     main-GEMM partial  part[kc][t][o] = x@W^T (K-chunk,
//                      split-K=2). BK=64, XOR-swizzled LDS (0 conflicts).
//  blocks [512,1536):  shrink partial, masked write: only idx[t]'s lora
//                      columns land in a_sel[kc][t][0..15].
// ---------------------------------------------------------------------------
__global__ __launch_bounds__(256, 4) void k12_kernel(
    const bf16* __restrict__ xb, const bf16* __restrict__ wb,
    const bf16* __restrict__ ab, const int* __restrict__ idx,
    bf16* __restrict__ part, float* __restrict__ a_sel)
{
    __shared__ __align__(16) bf16 sA[BM * BKM];   // 16 KB
    __shared__ __align__(16) bf16 sB[BN * BKM];   // 16 KB

    const int tid = threadIdx.x, wid = tid >> 6, lane = tid & 63;
    const int bid = blockIdx.x;

    if (bid < 512) {
        // ---------------- main GEMM partial (split-K=2) ----------------
        const int bn = bid & 31, bm = (bid >> 5) & 7, kc = bid >> 8;  // kc in {0,1}

        const bf16* __restrict__ gA = xb + (size_t)bm * BM * D_IN + kc * KCH;
        const bf16* __restrict__ gB = wb + (size_t)bn * BN * D_IN + kc * KCH;

        const int wm = (wid & 1) * 64, wn = (wid >> 1) * 64;
        const int lrow = lane & 15, quad = lane >> 4;

        v4f acc[4][4];
        const v4f vz = {0.f, 0.f, 0.f, 0.f};
#pragma unroll
        for (int mi = 0; mi < 4; ++mi)
#pragma unroll
            for (int ni = 0; ni < 4; ++ni) acc[mi][ni] = vz;

        for (int k0 = 0; k0 < KCH; k0 += BKM) {
            // slot s: row=s>>3, pos=s&7 holds global k-chunk pos^(row&7)
#pragma unroll
            for (int it = 0; it < 4; ++it) {
                const int s   = wid * 64 + lane + it * 256;
                const int row = s >> 3, pos = s & 7;
                const int kc8 = pos ^ (row & 7);
                const size_t goff = (size_t)row * D_IN + k0 + kc8 * 8;
                char* la_ = (char*)sA + (size_t)(wid * 64 + it * 256) * 16;
                char* lb_ = (char*)sB + (size_t)(wid * 64 + it * 256) * 16;
                ASYNC_COPY16(gA + goff, la_);
                ASYNC_COPY16(gB + goff, lb_);
            }
            __syncthreads();

#pragma unroll
            for (int ks = 0; ks < 2; ++ks) {
                bf16x8 af[4], bfv[4];
#pragma unroll
                for (int mi = 0; mi < 4; ++mi) {
                    const int row = wm + mi * 16 + lrow;
                    const int pos = (ks * 4 + quad) ^ (row & 7);
                    af[mi] = *(const bf16x8*)&sA[row * BKM + pos * 8];
                }
#pragma unroll
                for (int ni = 0; ni < 4; ++ni) {
                    const int row = wn + ni * 16 + lrow;
                    const int pos = (ks * 4 + quad) ^ (row & 7);
                    bfv[ni] = *(const bf16x8*)&sB[row * BKM + pos * 8];
                }
#pragma unroll
                for (int mi = 0; mi < 4; ++mi)
#pragma unroll
                    for (int ni = 0; ni < 4; ++ni)
                        acc[mi][ni] = __builtin_amdgcn_mfma_f32_16x16x32_bf16(
                            af[mi], bfv[ni], acc[mi][ni], 0, 0, 0);
            }
            __syncthreads();
        }

        bf16* __restrict__ op = part + (size_t)kc * PART_ELEMS;
        // C/D layout (16x16x32): col=lane&15, row=quad*4+reg
#pragma unroll
        for (int mi = 0; mi < 4; ++mi)
#pragma unroll
            for (int r = 0; r < 4; ++r) {
                const int t = bm * BM + wm + mi * 16 + quad * 4 + r;
#pragma unroll
                for (int ni = 0; ni < 4; ++ni) {
                    const int o = bn * BN + wn + ni * 16 + lrow;
                    op[(size_t)t * O_OUT + o] = (bf16)acc[mi][ni][r];
                }
            }
    } else {
        // ---------------- shrink GEMM partial (masked write) ----------------
        const int b2 = bid - 512;
        const int bm = b2 & 15, bn = (b2 >> 4) & 3, kc = b2 >> 6;

        bf16* sX = sA;                 // reuse first 4 KB of each buffer
        bf16* sAl = sB;

        const bf16* __restrict__ gX = xb + (size_t)bm * 64 * D_IN + kc * 256;
        const bf16* __restrict__ gA = ab + (size_t)bn * 64 * D_IN + kc * 256;

        const int wm = (wid & 1) * 32, wn = (wid >> 1) * 32;
        const int lrow = lane & 15, kq = (lane >> 4) * 8;
        const int row = tid >> 2, ch = tid & 3;

        v4f acc[2][2];
        const v4f vz = {0.f, 0.f, 0.f, 0.f};
        acc[0][0] = vz; acc[0][1] = vz; acc[1][0] = vz; acc[1][1] = vz;

        for (int k0 = 0; k0 < 256; k0 += 32) {
            const size_t goff = (size_t)row * D_IN + k0 + ch * 8;
            ASYNC_COPY16(gX + goff, (char*)sX + wid * 1024);
            ASYNC_COPY16(gA + goff, (char*)sAl + wid * 1024);
            __syncthreads();
            bf16x8 xf[2], af[2];
#pragma unroll
            for (int mi = 0; mi < 2; ++mi)
                xf[mi] = *(const bf16x8*)&sX[(wm + mi * 16 + lrow) * 32 + kq];
#pragma unroll
            for (int ni = 0; ni < 2; ++ni)
                af[ni] = *(const bf16x8*)&sAl[(wn + ni * 16 + lrow) * 32 + kq];
#pragma unroll
            for (int mi = 0; mi < 2; ++mi)
#pragma unroll
                for (int ni = 0; ni < 2; ++ni)
                    acc[mi][ni] = __builtin_amdgcn_mfma_f32_16x16x32_bf16(
                        xf[mi], af[ni], acc[mi][ni], 0, 0, 0);
            __syncthreads();
        }

        // Masked C-write: n-tile (bn*64+wn+ni*16) is 16-aligned; matches a
        // token's lora iff n-tile == idx[t]*16. 1 MB total vs 16 MB.
        float* __restrict__ op = a_sel + (size_t)kc * ASEL_STRIDE;
        const int colbase = bn * 64 + wn;
#pragma unroll
        for (int mi = 0; mi < 2; ++mi)
#pragma unroll
            for (int r = 0; r < 4; ++r) {
                const int t = bm * 64 + wm + mi * 16 + (lane >> 4) * 4 + r;
                const int l = idx[t];
                if (l >= 0) {
#pragma unroll
                    for (int ni = 0; ni < 2; ++ni) {
                        if (colbase + ni * 16 == l * 16)
                            op[(size_t)t * RANK + (lane & 15)] = acc[mi][ni][r];
                    }
                }
            }
    }
}

// ---------------------------------------------------------------------------
// K3: out[t,o] = part[0][t][o] + part[1][t][o] + bias[o] + LoRA expand.
// Grid (1024): one block per token; 16 o/thread (4 x v4f).
// ---------------------------------------------------------------------------
__global__ __launch_bounds__(256) void epilogue_kernel(
    const bf16* __restrict__ part, const float* __restrict__ bias,
    const bf16* __restrict__ lbb, const int* __restrict__ idx,
    const float* __restrict__ a_sel, float* __restrict__ out)
{
    const int t   = blockIdx.x;
    const int tid = threadIdx.x;
    const int l   = idx[t];

    // Parallel a_sel reduction: thread i in [0,256) = (kc=i>>4, r=i&15)
    __shared__ float sred[256];
    __shared__ float sa[RANK];
    {
        float v = 0.0f;
        if (l >= 0) {
            const int kc = tid >> 4, r = tid & 15;
            v = a_sel[(size_t)kc * ASEL_STRIDE + (size_t)t * RANK + r];
        }
        sred[tid] = v;
    }
    __syncthreads();
    if (tid < RANK) {
        float v = 0.0f;
#pragma unroll
        for (int kc = 0; kc < 16; ++kc) v += sred[kc * 16 + tid];
        sa[tid] = v;
    }
    __syncthreads();

#pragma unroll
    for (int c = 0; c < 4; ++c) {
        const int o = c * 1024 + tid * 4;
        const size_t po = (size_t)t * O_OUT + o;
        v4f s = *(const v4f*)&bias[o];
#pragma unroll
        for (int p = 0; p < 2; ++p) {
            bf16x4 pv = *(const bf16x4*)&part[(size_t)p * PART_ELEMS + po];
#pragma unroll
            for (int j = 0; j < 4; ++j) s[j] += (float)pv[j];
        }
        if (l >= 0) {
#pragma unroll
            for (int j = 0; j < 4; ++j) {
                const bf16* bp = lbb + ((size_t)l * O_OUT + o + j) * RANK;
                bf16x8 b0 = *(const bf16x8*)bp;
                bf16x8 b1 = *(const bf16x8*)(bp + 8);
                float y = 0.0f;
#pragma unroll
                for (int r = 0; r < 8; ++r) y += sa[r] * (float)b0[r];
#pragma unroll
                for (int r = 0; r < 8; ++r) y += sa[8 + r] * (float)b1[r];
                s[j] += y;
            }
        }
        *(v4f*)&out[po] = s;
    }
}

extern "C" void kernel_launch(void* const* d_in, const int* in_sizes, int n_in,
                              void* d_out, int out_size, void* d_ws, size_t ws_size,
                              hipStream_t stream) {
    const float* x    = (const float*)d_in[0];   // [1024, 4096]
    const float* wgt  = (const float*)d_in[1];   // [4096, 4096]
    const float* bias = (const float*)d_in[2];   // [4096]
    const float* la   = (const float*)d_in[3];   // [16,1,16,4096] = [256,4096]
    const float* lb   = (const float*)d_in[4];   // [16,1,4096,16]
    const int*   idx  = (const int*)d_in[5];     // [1024]
    float* out = (float*)d_out;

    char* ws = (char*)d_ws;
    bf16* wb  = (bf16*)(ws + WS_WB);
    bf16* xb  = (bf16*)(ws + WS_XB);
    bf16* ab  = (bf16*)(ws + WS_AB);
    bf16* lbb = (bf16*)(ws + WS_LBB);

    // Dead-input scratch (proven safe R10-R18; convert consumes both inputs
    // before k12 overwrites; stream-ordered; clobber cost measured ~0):
    //   fp32 W (64 MB) -> bf16 partial [2][1024][4096] (16 MB)
    //   fp32 x (16 MB) -> fp32 a_sel  [16][1024][16]   (1 MB)
    bf16*  partial = (bf16*)d_in[1];
    float* a_sel   = (float*)d_in[0];

    convert_kernel<<<dim3(11264), dim3(256), 0, stream>>>(
        wgt, x, la, lb, wb, xb, ab, lbb);
    k12_kernel<<<dim3(1536), dim3(256), 0, stream>>>(
        xb, wb, ab, idx, partial, a_sel);
    epilogue_kernel<<<dim3(T_TOK), dim3(256), 0, stream>>>(
        partial, bias, lbb, idx, a_sel, out);
}